// Round 1
// baseline (52.887 us; speedup 1.0000x reference)
//
#include <hip/hip_runtime.h>
#include <math.h>

#define NPTS 4096
#define EV_BLOCKS 1024
#define PAIR_BLOCKS 2048
#define BLK 256

// ---------------- block-level float reduction (deterministic) ----------------
__device__ inline float block_reduce_f(float v) {
    // wave64 shuffle reduce
    #pragma unroll
    for (int off = 32; off > 0; off >>= 1)
        v += __shfl_down(v, off, 64);
    __shared__ float smem[BLK / 64];
    const int lane = threadIdx.x & 63;
    const int wid  = threadIdx.x >> 6;
    if (lane == 0) smem[wid] = v;
    __syncthreads();
    float t = 0.f;
    if (threadIdx.x == 0) {
        #pragma unroll
        for (int w = 0; w < BLK / 64; ++w) t += smem[w];
    }
    return t;  // valid in thread 0 only
}

// ---------------- kernel 1: event intensity sum of d2 ----------------
__global__ void ev_kernel(const int* __restrict__ eu, const int* __restrict__ ev,
                          const float* __restrict__ et,
                          const float2* __restrict__ z0, const float2* __restrict__ v0,
                          float* __restrict__ partials, int nE) {
    float acc = 0.f;
    for (int i = blockIdx.x * blockDim.x + threadIdx.x; i < nE;
         i += gridDim.x * blockDim.x) {
        const int a = eu[i];
        const int b = ev[i];
        const float t = et[i];
        const float2 za = z0[a], zb = z0[b];
        const float2 va = v0[a], vb = v0[b];
        const float dx = (za.x - zb.x) + (va.x - vb.x) * t;
        const float dy = (za.y - zb.y) + (va.y - vb.y) * t;
        acc += dx * dx + dy * dy;
    }
    const float r = block_reduce_f(acc);
    if (threadIdx.x == 0) partials[blockIdx.x] = r;
}

// ---------------- kernel 2: non-event integral over ordered pairs i != j ----------------
__global__ void pair_kernel(const float2* __restrict__ z0, const float2* __restrict__ v0,
                            const float* __restrict__ beta_p, const float* __restrict__ t0_p,
                            const float* __restrict__ tn_p, float* __restrict__ partials) {
    const float b  = beta_p[0];
    const float t0 = t0_p[0];
    const float tn = tn_p[0];
    const float SQRT_PI = 1.77245385090551602729f;

    float acc = 0.f;
    const int total = NPTS * NPTS;
    for (int idx = blockIdx.x * blockDim.x + threadIdx.x; idx < total;
         idx += gridDim.x * blockDim.x) {
        const int i = idx >> 12;          // NPTS = 4096 = 2^12
        const int j = idx & (NPTS - 1);
        if (i == j) continue;

        const float2 zi = z0[i], zj = z0[j];
        const float2 vi = v0[i], vj = v0[j];
        const float a  = zi.x - zj.x;
        const float bb = zi.y - zj.y;
        const float m  = vi.x - vj.x;
        const float n  = vi.y - vj.y;

        const float s2    = m * m + n * n;
        const float inv_s = rsqrtf(s2);           // 1/s
        const float inv_s2 = inv_s * inv_s;       // 1/s2

        const float expo = ((b - bb * bb) * (m * m) + 2.0f * a * bb * m * n
                            - (n * n) * (a * a - b)) * inv_s2;
        const float am = a * m + bb * n;

        const float e1 = erff((s2 * t0 + am) * inv_s);
        const float e2 = erff((s2 * tn + am) * inv_s);

        acc += -SQRT_PI * __expf(expo) * (e1 - e2) * 0.5f * inv_s;
    }
    const float r = block_reduce_f(acc);
    if (threadIdx.x == 0) partials[blockIdx.x] = r;
}

// ---------------- kernel 3: final combine (double precision, deterministic) ----------------
__global__ void final_kernel(const float* __restrict__ evp, const float* __restrict__ pp,
                             const float* __restrict__ beta_p, float* __restrict__ out,
                             int nE) {
    __shared__ double sd[BLK];
    double se = 0.0;
    for (int i = threadIdx.x; i < EV_BLOCKS; i += BLK) se += (double)evp[i];
    double sp = 0.0;
    for (int i = threadIdx.x; i < PAIR_BLOCKS; i += BLK) sp += (double)pp[i];
    sd[threadIdx.x] = se + 0.5 * sp;   // (sum d2) + non_event_intensity
    __syncthreads();
    for (int s = BLK / 2; s > 0; s >>= 1) {
        if (threadIdx.x < s) sd[threadIdx.x] += sd[threadIdx.x + s];
        __syncthreads();
    }
    if (threadIdx.x == 0) {
        out[0] = (float)((double)nE * (double)beta_p[0] - sd[0]);
    }
}

extern "C" void kernel_launch(void* const* d_in, const int* in_sizes, int n_in,
                              void* d_out, int out_size, void* d_ws, size_t ws_size,
                              hipStream_t stream) {
    const int*    eu   = (const int*)d_in[0];
    const int*    ev   = (const int*)d_in[1];
    const float*  et   = (const float*)d_in[2];
    const float*  t0   = (const float*)d_in[3];
    const float*  tn   = (const float*)d_in[4];
    const float*  beta = (const float*)d_in[5];
    const float2* z0   = (const float2*)d_in[6];
    const float2* v0   = (const float2*)d_in[7];
    float* out = (float*)d_out;
    const int nE = in_sizes[0];

    float* ev_partials   = (float*)d_ws;                  // EV_BLOCKS floats
    float* pair_partials = ev_partials + EV_BLOCKS;       // PAIR_BLOCKS floats

    ev_kernel<<<EV_BLOCKS, BLK, 0, stream>>>(eu, ev, et, z0, v0, ev_partials, nE);
    pair_kernel<<<PAIR_BLOCKS, BLK, 0, stream>>>(z0, v0, beta, t0, tn, pair_partials);
    final_kernel<<<1, BLK, 0, stream>>>(ev_partials, pair_partials, beta, out, nE);
}

// Round 2
// 33.623 us; speedup vs baseline: 1.5729x; 1.5729x over previous
//
#include <hip/hip_runtime.h>
#include <math.h>

#define NPTS 4096
#define BLK 256
#define PAIR_BLOCKS 4096
#define EV_BLOCKS 1024
#define TOTAL_BLOCKS (PAIR_BLOCKS + EV_BLOCKS)   // 5120; every 5th block is an ev block
#define PAIR_CELLS (NPTS * NPTS / 2)             // 8,388,608 = 8 * PAIR_BLOCKS * BLK
#define PAIR_ITERS (PAIR_CELLS / (PAIR_BLOCKS * BLK))  // exactly 8

// ---------------- fast erf: Abramowitz-Stegun 7.1.26, |err| <= 1.5e-7 ----------------
__device__ __forceinline__ float fast_erf(float x) {
    const float ax = fabsf(x);
    const float t  = __builtin_amdgcn_rcpf(fmaf(0.3275911f, ax, 1.0f));
    float p = fmaf(t, 1.061405429f, -1.453152027f);
    p = fmaf(t, p, 1.421413741f);
    p = fmaf(t, p, -0.284496736f);
    p = fmaf(t, p, 0.254829592f);
    p *= t;
    const float e = __expf(-ax * ax);
    const float r = fmaf(-p, e, 1.0f);
    return copysignf(r, x);
}

// ---------------- block-level float reduction (deterministic) ----------------
__device__ __forceinline__ float block_reduce_f(float v) {
    #pragma unroll
    for (int off = 32; off > 0; off >>= 1)
        v += __shfl_down(v, off, 64);
    __shared__ float smem[BLK / 64];
    const int lane = threadIdx.x & 63;
    const int wid  = threadIdx.x >> 6;
    if (lane == 0) smem[wid] = v;
    __syncthreads();
    float t = 0.f;
    if (threadIdx.x == 0) {
        #pragma unroll
        for (int w = 0; w < BLK / 64; ++w) t += smem[w];
    }
    return t;  // valid in thread 0 only
}

// ---------------- fused kernel: pair integral + event intensity ----------------
__global__ __launch_bounds__(BLK) void fused_kernel(
        const int* __restrict__ eu, const int* __restrict__ ev,
        const float* __restrict__ et,
        const float2* __restrict__ z0, const float2* __restrict__ v0,
        const float* __restrict__ beta_p, const float* __restrict__ t0_p,
        const float* __restrict__ tn_p,
        float* __restrict__ ev_partials, float* __restrict__ pair_partials,
        int nE) {
    const int bid = blockIdx.x;
    const bool is_ev = (bid % 5 == 0);

    if (is_ev) {
        // ----- event part: sum_e ||dz + dv*t||^2 -----
        const int ev_id = bid / 5;                       // [0, EV_BLOCKS)
        float acc = 0.f;
        for (int i = ev_id * BLK + threadIdx.x; i < nE; i += EV_BLOCKS * BLK) {
            const int a = eu[i];
            const int b = ev[i];
            const float t = et[i];
            const float2 za = z0[a], zb = z0[b];
            const float2 va = v0[a], vb = v0[b];
            const float dx = (za.x - zb.x) + (va.x - vb.x) * t;
            const float dy = (za.y - zb.y) + (va.y - vb.y) * t;
            acc += dx * dx + dy * dy;
        }
        const float r = block_reduce_f(acc);
        if (threadIdx.x == 0) ev_partials[ev_id] = r;
    } else {
        // ----- pair part: each unordered pair i<j exactly once -----
        const int pair_id = bid - (bid / 5 + 1);         // [0, PAIR_BLOCKS)
        const float b  = beta_p[0];
        const float t0 = t0_p[0];
        const float tn = tn_p[0];
        // integ = -sqrt(pi)/2 * e^b * exp(-q^2) * (e1-e2) / s,  q = (bb*m - a*n)/s
        const float C = -0.88622692545275801365f * __expf(b);   // -sqrt(pi)/2 * e^b

        float acc = 0.f;
        const int tid = pair_id * BLK + threadIdx.x;
        #pragma unroll
        for (int it = 0; it < PAIR_ITERS; ++it) {
            const int idx = tid + it * (PAIR_BLOCKS * BLK);
            int i = idx >> 12;            // [0, 2048)
            int j = idx & (NPTS - 1);
            if (j == i) continue;         // wasted diagonal lanes: 1/4096
            if (j < i) { i = NPTS - 1 - i; j = NPTS - 1 - j; }  // fold to upper triangle

            const float2 zi = z0[i], zj = z0[j];
            const float2 vi = v0[i], vj = v0[j];
            const float a  = zi.x - zj.x;
            const float bb = zi.y - zj.y;
            const float m  = vi.x - vj.x;
            const float n  = vi.y - vj.y;

            const float s2    = fmaf(m, m, n * n);
            const float inv_s = __builtin_amdgcn_rsqf(s2);
            const float cross = fmaf(bb, m, -a * n);
            const float am    = fmaf(a, m, bb * n);

            const float q  = cross * inv_s;
            const float E  = __expf(-q * q);

            const float e1 = fast_erf(fmaf(s2, t0, am) * inv_s);
            const float e2 = fast_erf(fmaf(s2, tn, am) * inv_s);

            acc += (C * E) * (e1 - e2) * inv_s;
        }
        const float r = block_reduce_f(acc);
        if (threadIdx.x == 0) pair_partials[pair_id] = r;
    }
}

// ---------------- final combine (double precision, deterministic) ----------------
__global__ void final_kernel(const float* __restrict__ evp, const float* __restrict__ pp,
                             const float* __restrict__ beta_p, float* __restrict__ out,
                             int nE) {
    __shared__ double sd[BLK];
    double se = 0.0;
    for (int i = threadIdx.x; i < EV_BLOCKS; i += BLK) se += (double)evp[i];
    double sp = 0.0;
    for (int i = threadIdx.x; i < PAIR_BLOCKS; i += BLK) sp += (double)pp[i];
    sd[threadIdx.x] = se + sp;   // (sum d2) + non_event_intensity
    __syncthreads();
    for (int s = BLK / 2; s > 0; s >>= 1) {
        if (threadIdx.x < s) sd[threadIdx.x] += sd[threadIdx.x + s];
        __syncthreads();
    }
    if (threadIdx.x == 0) {
        out[0] = (float)((double)nE * (double)beta_p[0] - sd[0]);
    }
}

extern "C" void kernel_launch(void* const* d_in, const int* in_sizes, int n_in,
                              void* d_out, int out_size, void* d_ws, size_t ws_size,
                              hipStream_t stream) {
    const int*    eu   = (const int*)d_in[0];
    const int*    ev   = (const int*)d_in[1];
    const float*  et   = (const float*)d_in[2];
    const float*  t0   = (const float*)d_in[3];
    const float*  tn   = (const float*)d_in[4];
    const float*  beta = (const float*)d_in[5];
    const float2* z0   = (const float2*)d_in[6];
    const float2* v0   = (const float2*)d_in[7];
    float* out = (float*)d_out;
    const int nE = in_sizes[0];

    float* ev_partials   = (float*)d_ws;                  // EV_BLOCKS floats
    float* pair_partials = ev_partials + EV_BLOCKS;       // PAIR_BLOCKS floats

    fused_kernel<<<TOTAL_BLOCKS, BLK, 0, stream>>>(eu, ev, et, z0, v0, beta, t0, tn,
                                                   ev_partials, pair_partials, nE);
    final_kernel<<<1, BLK, 0, stream>>>(ev_partials, pair_partials, beta, out, nE);
}